// Round 2
// baseline (257.518 us; speedup 1.0000x reference)
//
#include <hip/hip_runtime.h>
#include <math.h>

static constexpr int NN = 30000;   // nodes
static constexpr int NF = 512;     // in features
static constexpr int NH = 128;     // hidden
static constexpr int NC = 64;      // classes

// ---------------- register bitonic sort of 32 (ascending) ----------------
__device__ __forceinline__ void cswap(float& a, float& b) {
  float lo = fminf(a, b), hi = fmaxf(a, b);
  a = lo; b = hi;
}

__device__ __forceinline__ void sort32(float v[32]) {
  #pragma unroll
  for (int k = 2; k <= 32; k <<= 1) {
    #pragma unroll
    for (int j = k >> 1; j > 0; j >>= 1) {
      #pragma unroll
      for (int i = 0; i < 32; ++i) {
        const int l = i ^ j;
        if (l > i) {
          if ((i & k) == 0) cswap(v[i], v[l]);   // ascending block
          else              cswap(v[l], v[i]);   // descending block
        }
      }
    }
  }
}

// ---------------- k1: h0 = x @ W1  (fp32 tiled) ----------------
// M-tile 64 x N 128 (full), K-tile 32, 256 threads, 4 rows x 8 cols / thread.
__global__ __launch_bounds__(256) void k1_gemm1(const float* __restrict__ x,
                                                const float* __restrict__ W1,
                                                float* __restrict__ h0) {
  __shared__ float As[32][68];    // [k][row], row-pad 64->68 keeps rows 16B-aligned
  __shared__ float Bs[32][128];   // [k][col]
  const int tid = threadIdx.x;
  const int m0  = blockIdx.x * 64;
  const int tc  = tid & 15;   // col group (8 cols)
  const int tr  = tid >> 4;   // row group (4 rows)

  float acc[4][8];
  #pragma unroll
  for (int r = 0; r < 4; ++r)
    #pragma unroll
    for (int c = 0; c < 8; ++c) acc[r][c] = 0.f;

  for (int k0 = 0; k0 < NF; k0 += 32) {
    // A tile: 64 rows x 32 k, store transposed As[k][row]
    #pragma unroll
    for (int it = 0; it < 2; ++it) {
      const int p   = tid + it * 256;   // float4 index 0..511
      const int row = p >> 3;           // 8 float4 per row
      const int c4  = p & 7;
      int grow = m0 + row;
      if (grow > NN - 1) grow = NN - 1; // tail clamp (stores are guarded)
      const float4 a = *reinterpret_cast<const float4*>(&x[grow * NF + k0 + c4 * 4]);
      As[c4 * 4 + 0][row] = a.x;
      As[c4 * 4 + 1][row] = a.y;
      As[c4 * 4 + 2][row] = a.z;
      As[c4 * 4 + 3][row] = a.w;
    }
    // B tile: 32 k x 128 cols
    #pragma unroll
    for (int it = 0; it < 4; ++it) {
      const int p   = tid + it * 256;   // float4 index 0..1023
      const int row = p >> 5;           // 32 float4 per row
      const int c4  = p & 31;
      *reinterpret_cast<float4*>(&Bs[row][c4 * 4]) =
          *reinterpret_cast<const float4*>(&W1[(k0 + row) * NH + c4 * 4]);
    }
    __syncthreads();

    #pragma unroll
    for (int kk = 0; kk < 32; ++kk) {
      const float4 a  = *reinterpret_cast<const float4*>(&As[kk][tr * 4]);
      const float4 b0 = *reinterpret_cast<const float4*>(&Bs[kk][tc * 8]);
      const float4 b1 = *reinterpret_cast<const float4*>(&Bs[kk][tc * 8 + 4]);
      const float av[4] = {a.x, a.y, a.z, a.w};
      const float bv[8] = {b0.x, b0.y, b0.z, b0.w, b1.x, b1.y, b1.z, b1.w};
      #pragma unroll
      for (int r = 0; r < 4; ++r)
        #pragma unroll
        for (int c = 0; c < 8; ++c)
          acc[r][c] = fmaf(av[r], bv[c], acc[r][c]);
    }
    __syncthreads();
  }

  #pragma unroll
  for (int r = 0; r < 4; ++r) {
    const int grow = m0 + tr * 4 + r;
    if (grow < NN) {
      const float4 o0 = make_float4(acc[r][0], acc[r][1], acc[r][2], acc[r][3]);
      const float4 o1 = make_float4(acc[r][4], acc[r][5], acc[r][6], acc[r][7]);
      *reinterpret_cast<float4*>(&h0[grow * NH + tc * 8 + 0]) = o0;
      *reinterpret_cast<float4*>(&h0[grow * NH + tc * 8 + 4]) = o1;
    }
  }
}

// ---------------- k2: h = relu(median(h0 gather)+b1); z = h @ W2 ----------------
// 2 nodes / block; 128 threads per node (one per hidden feature).
__global__ __launch_bounds__(256) void k2_median1_gemm2(const float* __restrict__ h0,
                                                        const int* __restrict__ nbr,
                                                        const float* __restrict__ b1,
                                                        const float* __restrict__ W2,
                                                        float* __restrict__ z) {
  __shared__ int   nb[2][32];
  __shared__ float hs[2][NH];
  const int tid = threadIdx.x;
  const int g   = tid >> 7;       // node slot 0/1
  const int f   = tid & 127;      // hidden feature
  const int i   = blockIdx.x * 2 + g;   // node id (grid covers exactly NN)

  if (f < 32) nb[g][f] = nbr[i * 32 + f];
  __syncthreads();

  float v[32];
  #pragma unroll
  for (int k = 0; k < 32; ++k) {
    int idx = i + nb[g][k] + 1;
    if (idx >= NN) idx -= NN;
    v[k] = h0[idx * NH + f];
  }
  const float self = h0[i * NH + f];

  sort32(v);
  const float med = fminf(fmaxf(self, v[15]), v[16]);  // lower median of 33
  const float h   = fmaxf(med + b1[f], 0.f);

  hs[g][f] = h;
  __syncthreads();

  if (f < NC) {
    float acc = 0.f;
    #pragma unroll 8
    for (int kk = 0; kk < NH; ++kk)
      acc = fmaf(hs[g][kk], W2[kk * NC + f], acc);
    z[i * NC + f] = acc;
  }
}

// ---------------- k3: out = log_softmax(median(z gather)+b2) ----------------
// 4 nodes / block; 64 lanes per node (one wave per node).
__global__ __launch_bounds__(256) void k3_median2_lsm(const float* __restrict__ z,
                                                      const int* __restrict__ nbr,
                                                      const float* __restrict__ b2,
                                                      float* __restrict__ out) {
  __shared__ int nb[4][32];
  const int tid = threadIdx.x;
  const int g   = tid >> 6;
  const int f   = tid & 63;
  const int i   = blockIdx.x * 4 + g;

  if (f < 32) nb[g][f] = nbr[i * 32 + f];
  __syncthreads();

  float v[32];
  #pragma unroll
  for (int k = 0; k < 32; ++k) {
    int idx = i + nb[g][k] + 1;
    if (idx >= NN) idx -= NN;
    v[k] = z[idx * NC + f];
  }
  const float self = z[i * NC + f];

  sort32(v);
  const float med = fminf(fmaxf(self, v[15]), v[16]);
  const float o   = med + b2[f];

  // log-softmax across the 64 lanes of this wave
  float m = o;
  #pragma unroll
  for (int d = 1; d < 64; d <<= 1) m = fmaxf(m, __shfl_xor(m, d, 64));
  float e = __expf(o - m);
  float s = e;
  #pragma unroll
  for (int d = 1; d < 64; d <<= 1) s += __shfl_xor(s, d, 64);

  out[i * NC + f] = (o - m) - __logf(s);
}

// ---------------- launch ----------------
extern "C" void kernel_launch(void* const* d_in, const int* in_sizes, int n_in,
                              void* d_out, int out_size, void* d_ws, size_t ws_size,
                              hipStream_t stream) {
  const float* x   = (const float*)d_in[0];
  const int*   nbr = (const int*)d_in[1];
  const float* W1  = (const float*)d_in[2];
  const float* b1  = (const float*)d_in[3];
  const float* W2  = (const float*)d_in[4];
  const float* b2  = (const float*)d_in[5];
  float* outp = (float*)d_out;

  float* h0 = (float*)d_ws;                                   // NN*NH floats = 15.36 MB
  float* zz = (float*)((char*)d_ws + (size_t)NN * NH * 4);    // NN*NC floats = 7.68 MB

  k1_gemm1<<<(NN + 63) / 64, 256, 0, stream>>>(x, W1, h0);
  k2_median1_gemm2<<<NN / 2, 256, 0, stream>>>(h0, nbr, b1, W2, zz);
  k3_median2_lsm<<<NN / 4, 256, 0, stream>>>(zz, nbr, b2, outp);
}

// Round 3
// 254.781 us; speedup vs baseline: 1.0107x; 1.0107x over previous
//
#include <hip/hip_runtime.h>
#include <hip/hip_bf16.h>
#include <math.h>

static constexpr int NN = 30000;   // nodes
static constexpr int NF = 512;     // in features
static constexpr int NH = 128;     // hidden
static constexpr int NC = 64;      // classes

typedef unsigned int uint32;

__device__ __forceinline__ float bf_lo(uint32 p) { return __uint_as_float(p << 16); }
__device__ __forceinline__ float bf_hi(uint32 p) { return __uint_as_float(p & 0xffff0000u); }

__device__ __forceinline__ void cswap(float& a, float& b) {
  float lo = fminf(a, b), hi = fmaxf(a, b);
  a = lo; b = hi;
}

// Given v[0..31], computes the rank-15 and rank-16 (0-indexed) order statistics.
// Method: bitonic-sort each 16-half ascending, then use the merge identity:
//   M[15] = max_i min(A[i], B[15-i]),  M[16] = min_i max(A[i], B[15-i]).
__device__ __forceinline__ void medsel32(float v[32], float& m15, float& m16) {
  #pragma unroll
  for (int k = 2; k <= 16; k <<= 1) {
    #pragma unroll
    for (int j = k >> 1; j > 0; j >>= 1) {
      #pragma unroll
      for (int h = 0; h < 2; ++h) {
        #pragma unroll
        for (int i = 0; i < 16; ++i) {
          const int l = i ^ j;
          if (l > i) {
            const int a = h * 16 + i, b = h * 16 + l;
            if ((i & k) == 0) cswap(v[a], v[b]);
            else              cswap(v[b], v[a]);
          }
        }
      }
    }
  }
  m15 = fminf(v[0], v[31]);   // min(A[0], B[15])
  m16 = fmaxf(v[0], v[31]);   // max(A[0], B[15])
  #pragma unroll
  for (int i = 1; i < 16; ++i) {
    m15 = fmaxf(m15, fminf(v[i], v[31 - i]));
    m16 = fminf(m16, fmaxf(v[i], v[31 - i]));
  }
}

// ---------------- k1: h0b = bf16(x @ W1)  (fp32 math, 128x128 tile) ----------------
__global__ __launch_bounds__(256) void k1_gemm1(const float* __restrict__ x,
                                                const float* __restrict__ W1,
                                                __hip_bfloat16* __restrict__ h0b) {
  __shared__ float As[32][132];   // [k][row], pad 128->132
  __shared__ float Bs[32][128];   // [k][col]
  const int tid = threadIdx.x;
  const int m0  = blockIdx.x * 128;
  const int tr  = tid >> 4;   // 16 row groups of 8
  const int tc  = tid & 15;   // 16 col groups of 8

  float acc[8][8];
  #pragma unroll
  for (int r = 0; r < 8; ++r)
    #pragma unroll
    for (int c = 0; c < 8; ++c) acc[r][c] = 0.f;

  for (int k0 = 0; k0 < NF; k0 += 32) {
    // A tile: 128 rows x 32 k -> transposed As[k][row]; 1024 float4 / 256 thr
    #pragma unroll
    for (int it = 0; it < 4; ++it) {
      const int p   = tid + it * 256;
      const int row = p >> 3;       // 8 float4 per row
      const int c4  = p & 7;
      int gr = m0 + row;
      if (gr >= NN) gr = NN - 1;    // tail clamp (stores guarded)
      const float4 a = *reinterpret_cast<const float4*>(&x[(size_t)gr * NF + k0 + c4 * 4]);
      As[c4 * 4 + 0][row] = a.x;
      As[c4 * 4 + 1][row] = a.y;
      As[c4 * 4 + 2][row] = a.z;
      As[c4 * 4 + 3][row] = a.w;
    }
    // B tile: 32 k x 128 cols; 1024 float4 / 256 thr
    #pragma unroll
    for (int it = 0; it < 4; ++it) {
      const int p   = tid + it * 256;
      const int row = p >> 5;       // 32 float4 per row
      const int c4  = p & 31;
      *reinterpret_cast<float4*>(&Bs[row][c4 * 4]) =
          *reinterpret_cast<const float4*>(&W1[(k0 + row) * NH + c4 * 4]);
    }
    __syncthreads();

    #pragma unroll
    for (int kk = 0; kk < 32; ++kk) {
      const float4 a0 = *reinterpret_cast<const float4*>(&As[kk][tr * 8 + 0]);
      const float4 a1 = *reinterpret_cast<const float4*>(&As[kk][tr * 8 + 4]);
      const float4 b0 = *reinterpret_cast<const float4*>(&Bs[kk][tc * 8 + 0]);
      const float4 b1 = *reinterpret_cast<const float4*>(&Bs[kk][tc * 8 + 4]);
      const float av[8] = {a0.x, a0.y, a0.z, a0.w, a1.x, a1.y, a1.z, a1.w};
      const float bv[8] = {b0.x, b0.y, b0.z, b0.w, b1.x, b1.y, b1.z, b1.w};
      #pragma unroll
      for (int r = 0; r < 8; ++r)
        #pragma unroll
        for (int c = 0; c < 8; ++c)
          acc[r][c] = fmaf(av[r], bv[c], acc[r][c]);
    }
    __syncthreads();
  }

  #pragma unroll
  for (int r = 0; r < 8; ++r) {
    const int gr = m0 + tr * 8 + r;
    if (gr < NN) {
      alignas(16) __hip_bfloat16 t[8];
      #pragma unroll
      for (int c = 0; c < 8; ++c) t[c] = __float2bfloat16(acc[r][c]);
      *reinterpret_cast<uint4*>(&h0b[(size_t)gr * NH + tc * 8]) =
          *reinterpret_cast<const uint4*>(t);
    }
  }
}

// ---------------- k2: h = relu(median33(h0b)+b1); zb = bf16(h @ W2) ----------------
// 4 nodes/block, 64 lanes/node, 2 features/lane (packed bf16x2 loads).
__global__ __launch_bounds__(256) void k2_median1_gemm2(const __hip_bfloat16* __restrict__ h0b,
                                                        const int* __restrict__ nbr,
                                                        const float* __restrict__ b1,
                                                        const float* __restrict__ W2,
                                                        __hip_bfloat16* __restrict__ zb) {
  __shared__ int   nb[4][32];
  __shared__ float hs[4][NH];
  const int tid  = threadIdx.x;
  const int g    = tid >> 6;
  const int lane = tid & 63;
  const int i    = blockIdx.x * 4 + g;

  if (lane < 32) nb[g][lane] = nbr[i * 32 + lane];
  __syncthreads();

  const uint32* hrow = reinterpret_cast<const uint32*>(h0b);  // 64 uints per row
  uint32 pr[32];
  #pragma unroll
  for (int k = 0; k < 32; ++k) {
    int idx = i + nb[g][k] + 1;
    if (idx >= NN) idx -= NN;
    pr[k] = hrow[idx * 64 + lane];
  }
  const uint32 ps = hrow[i * 64 + lane];

  float v[32], m15, m16;
  #pragma unroll
  for (int k = 0; k < 32; ++k) v[k] = bf_lo(pr[k]);
  medsel32(v, m15, m16);
  const float hA = fmaxf(fminf(fmaxf(bf_lo(ps), m15), m16) + b1[lane * 2 + 0], 0.f);

  #pragma unroll
  for (int k = 0; k < 32; ++k) v[k] = bf_hi(pr[k]);
  medsel32(v, m15, m16);
  const float hB = fmaxf(fminf(fmaxf(bf_hi(ps), m15), m16) + b1[lane * 2 + 1], 0.f);

  hs[g][lane * 2 + 0] = hA;
  hs[g][lane * 2 + 1] = hB;
  __syncthreads();

  // GEMM2: one output column per lane; hs broadcast from LDS, W2 via L1/L2.
  float acc = 0.f;
  #pragma unroll 16
  for (int kk = 0; kk < NH; ++kk)
    acc = fmaf(hs[g][kk], W2[kk * NC + lane], acc);
  zb[i * NC + lane] = __float2bfloat16(acc);
}

// ---------------- k3: out = log_softmax(median33(zb)+b2) ----------------
// 8 nodes/block, 32 lanes/node, 2 classes/lane (packed bf16x2 loads).
__global__ __launch_bounds__(256) void k3_median2_lsm(const __hip_bfloat16* __restrict__ zb,
                                                      const int* __restrict__ nbr,
                                                      const float* __restrict__ b2,
                                                      float* __restrict__ out) {
  __shared__ int nb[8][32];
  const int tid  = threadIdx.x;
  const int g    = tid >> 5;
  const int lane = tid & 31;
  const int i    = blockIdx.x * 8 + g;

  nb[g][lane] = nbr[i * 32 + lane];
  __syncthreads();

  const uint32* zrow = reinterpret_cast<const uint32*>(zb);  // 32 uints per row
  uint32 pr[32];
  #pragma unroll
  for (int k = 0; k < 32; ++k) {
    int idx = i + nb[g][k] + 1;
    if (idx >= NN) idx -= NN;
    pr[k] = zrow[idx * 32 + lane];
  }
  const uint32 ps = zrow[i * 32 + lane];

  float v[32], m15, m16;
  #pragma unroll
  for (int k = 0; k < 32; ++k) v[k] = bf_lo(pr[k]);
  medsel32(v, m15, m16);
  const float oA = fminf(fmaxf(bf_lo(ps), m15), m16) + b2[lane * 2 + 0];

  #pragma unroll
  for (int k = 0; k < 32; ++k) v[k] = bf_hi(pr[k]);
  medsel32(v, m15, m16);
  const float oB = fminf(fmaxf(bf_hi(ps), m15), m16) + b2[lane * 2 + 1];

  // log-softmax over 64 classes = 2/lane x 32 lanes (width-32 shuffles)
  float m = fmaxf(oA, oB);
  #pragma unroll
  for (int d = 1; d < 32; d <<= 1) m = fmaxf(m, __shfl_xor(m, d, 32));
  float s = __expf(oA - m) + __expf(oB - m);
  #pragma unroll
  for (int d = 1; d < 32; d <<= 1) s += __shfl_xor(s, d, 32);
  const float ls = __logf(s);

  *reinterpret_cast<float2*>(&out[i * NC + lane * 2]) =
      make_float2(oA - m - ls, oB - m - ls);
}

// ---------------- launch ----------------
extern "C" void kernel_launch(void* const* d_in, const int* in_sizes, int n_in,
                              void* d_out, int out_size, void* d_ws, size_t ws_size,
                              hipStream_t stream) {
  const float* x   = (const float*)d_in[0];
  const int*   nbr = (const int*)d_in[1];
  const float* W1  = (const float*)d_in[2];
  const float* b1  = (const float*)d_in[3];
  const float* W2  = (const float*)d_in[4];
  const float* b2  = (const float*)d_in[5];
  float* outp = (float*)d_out;

  __hip_bfloat16* h0b = (__hip_bfloat16*)d_ws;                           // 7.68 MB
  __hip_bfloat16* zb  = (__hip_bfloat16*)((char*)d_ws + (size_t)NN * NH * 2);  // 3.84 MB

  k1_gemm1<<<(NN + 127) / 128, 256, 0, stream>>>(x, W1, h0b);
  k2_median1_gemm2<<<NN / 4, 256, 0, stream>>>(h0b, nbr, b1, W2, zb);
  k3_median2_lsm<<<NN / 8, 256, 0, stream>>>(zb, nbr, b2, outp);
}

// Round 5
// 212.731 us; speedup vs baseline: 1.2105x; 1.1977x over previous
//
#include <hip/hip_runtime.h>
#include <hip/hip_bf16.h>
#include <math.h>

static constexpr int NN = 30000;   // nodes
static constexpr int NF = 512;     // in features
static constexpr int NH = 128;     // hidden
static constexpr int NC = 64;      // classes

typedef unsigned int uint32;
typedef __attribute__((ext_vector_type(8))) short bf16x8;
typedef __attribute__((ext_vector_type(4))) float f32x4;

__device__ __forceinline__ float bf_lo(uint32 p) { return __uint_as_float(p << 16); }
__device__ __forceinline__ float bf_hi(uint32 p) { return __uint_as_float(p & 0xffff0000u); }

__device__ __forceinline__ unsigned short bfbits(float f) {
  __hip_bfloat16 h = __float2bfloat16(f);   // RNE
  return *reinterpret_cast<unsigned short*>(&h);
}

__device__ __forceinline__ void cswap(float& a, float& b) {
  float lo = fminf(a, b), hi = fmaxf(a, b);
  a = lo; b = hi;
}

// rank-15 / rank-16 (0-indexed) of v[0..31]: sort 16-halves + bitonic-merge identity
__device__ __forceinline__ void medsel32(float v[32], float& m15, float& m16) {
  #pragma unroll
  for (int k = 2; k <= 16; k <<= 1) {
    #pragma unroll
    for (int j = k >> 1; j > 0; j >>= 1) {
      #pragma unroll
      for (int h = 0; h < 2; ++h) {
        #pragma unroll
        for (int i = 0; i < 16; ++i) {
          const int l = i ^ j;
          if (l > i) {
            const int a = h * 16 + i, b = h * 16 + l;
            if ((i & k) == 0) cswap(v[a], v[b]);
            else              cswap(v[b], v[a]);
          }
        }
      }
    }
  }
  m15 = fminf(v[0], v[31]);
  m16 = fmaxf(v[0], v[31]);
  #pragma unroll
  for (int i = 1; i < 16; ++i) {
    m15 = fmaxf(m15, fminf(v[i], v[31 - i]));
    m16 = fminf(m16, fmaxf(v[i], v[31 - i]));
  }
}

// ---------------- k0: W1 fp32 -> bf16 in MFMA-fragment order ----------------
// Bp element index = ((kt*8 + nt)*64 + lane)*8 + j  where lane = ks*16 + ct,
// maps W1[k = kt*32 + ks*8 + j][col = nt*16 + ct].
__global__ __launch_bounds__(256) void k0_prepW1(const float* __restrict__ W1,
                                                 unsigned short* __restrict__ Bp) {
  const int g  = blockIdx.x * 256 + threadIdx.x;  // 0..8191 fragment-lane groups
  const int kt = g >> 9;
  const int r  = g & 511;
  const int nt = r >> 6;
  const int l  = r & 63;
  const int ks = l >> 4;
  const int ct = l & 15;
  alignas(16) unsigned short t[8];
  #pragma unroll
  for (int j = 0; j < 8; ++j)
    t[j] = bfbits(W1[(kt * 32 + ks * 8 + j) * NH + nt * 16 + ct]);
  *reinterpret_cast<uint4*>(&Bp[(size_t)g * 8]) = *reinterpret_cast<const uint4*>(t);
}

// ---------------- k1: h0b = bf16(x @ W1) via MFMA, no LDS ----------------
// 469 blocks x 4 waves; wave = 16 rows x 128 cols; K=512 in 16 steps of 32.
__global__ __launch_bounds__(256) void k1_gemm1(const float* __restrict__ x,
                                                const unsigned short* __restrict__ Bp,
                                                __hip_bfloat16* __restrict__ h0b) {
  const int tid = threadIdx.x;
  const int w   = tid >> 6;
  const int l   = tid & 63;
  const int m0  = blockIdx.x * 64 + w * 16;

  int arow = m0 + (l & 15);
  if (arow >= NN) arow = NN - 1;          // tail clamp; stores guarded
  const float* xrow = x + (size_t)arow * NF + (l >> 4) * 8;

  f32x4 acc[8];
  #pragma unroll
  for (int nt = 0; nt < 8; ++nt) acc[nt] = (f32x4){0.f, 0.f, 0.f, 0.f};

  #pragma unroll 2
  for (int kt = 0; kt < 16; ++kt) {
    const float4 a0 = *reinterpret_cast<const float4*>(xrow + kt * 32);
    const float4 a1 = *reinterpret_cast<const float4*>(xrow + kt * 32 + 4);
    union { bf16x8 v; unsigned short u[8]; } A;
    const float av[8] = {a0.x, a0.y, a0.z, a0.w, a1.x, a1.y, a1.z, a1.w};
    #pragma unroll
    for (int j = 0; j < 8; ++j) A.u[j] = bfbits(av[j]);

    const unsigned short* bbase = Bp + (size_t)kt * 4096 + l * 8;
    #pragma unroll
    for (int nt = 0; nt < 8; ++nt) {
      const bf16x8 B = *reinterpret_cast<const bf16x8*>(bbase + nt * 512);
      acc[nt] = __builtin_amdgcn_mfma_f32_16x16x32_bf16(A.v, B, acc[nt], 0, 0, 0);
    }
  }

  // C/D layout: col = l&15, row = (l>>4)*4 + q  [measured m89/m91]
  const int rbase = m0 + (l >> 4) * 4;
  const int cbase = l & 15;
  #pragma unroll
  for (int q = 0; q < 4; ++q) {
    const int rr = rbase + q;
    if (rr < NN) {
      #pragma unroll
      for (int nt = 0; nt < 8; ++nt)
        h0b[(size_t)rr * NH + nt * 16 + cbase] = __float2bfloat16(acc[nt][q]);
    }
  }
}

// ---------------- k2: h = relu(median33(h0b)+b1); zb = bf16(h @ W2) ----------------
__global__ __launch_bounds__(256) void k2_median1_gemm2(const __hip_bfloat16* __restrict__ h0b,
                                                        const int* __restrict__ nbr,
                                                        const float* __restrict__ b1,
                                                        const float* __restrict__ W2,
                                                        __hip_bfloat16* __restrict__ zb) {
  __shared__ int   nb[4][32];
  __shared__ float hs[4][NH];
  const int tid  = threadIdx.x;
  const int g    = tid >> 6;
  const int lane = tid & 63;
  const int i    = blockIdx.x * 4 + g;

  if (lane < 32) nb[g][lane] = nbr[i * 32 + lane];
  __syncthreads();

  const uint32* hrow = reinterpret_cast<const uint32*>(h0b);  // 64 uints per row
  uint32 pr[32];
  #pragma unroll
  for (int k = 0; k < 32; ++k) {
    int idx = i + nb[g][k] + 1;
    if (idx >= NN) idx -= NN;
    pr[k] = hrow[idx * 64 + lane];
  }
  const uint32 ps = hrow[i * 64 + lane];

  float v[32], m15, m16;
  #pragma unroll
  for (int k = 0; k < 32; ++k) v[k] = bf_lo(pr[k]);
  medsel32(v, m15, m16);
  const float hA = fmaxf(fminf(fmaxf(bf_lo(ps), m15), m16) + b1[lane * 2 + 0], 0.f);

  #pragma unroll
  for (int k = 0; k < 32; ++k) v[k] = bf_hi(pr[k]);
  medsel32(v, m15, m16);
  const float hB = fmaxf(fminf(fmaxf(bf_hi(ps), m15), m16) + b1[lane * 2 + 1], 0.f);

  hs[g][lane * 2 + 0] = hA;
  hs[g][lane * 2 + 1] = hB;
  __syncthreads();

  float acc = 0.f;
  #pragma unroll 16
  for (int kk = 0; kk < NH; ++kk)
    acc = fmaf(hs[g][kk], W2[kk * NC + lane], acc);
  zb[i * NC + lane] = __float2bfloat16(acc);
}

// ---------------- k3: out = log_softmax(median33(zb)+b2) ----------------
__global__ __launch_bounds__(256) void k3_median2_lsm(const __hip_bfloat16* __restrict__ zb,
                                                      const int* __restrict__ nbr,
                                                      const float* __restrict__ b2,
                                                      float* __restrict__ out) {
  __shared__ int nb[8][32];
  const int tid  = threadIdx.x;
  const int g    = tid >> 5;
  const int lane = tid & 31;
  const int i    = blockIdx.x * 8 + g;

  nb[g][lane] = nbr[i * 32 + lane];
  __syncthreads();

  const uint32* zrow = reinterpret_cast<const uint32*>(zb);  // 32 uints per row
  uint32 pr[32];
  #pragma unroll
  for (int k = 0; k < 32; ++k) {
    int idx = i + nb[g][k] + 1;
    if (idx >= NN) idx -= NN;
    pr[k] = zrow[idx * 32 + lane];
  }
  const uint32 ps = zrow[i * 32 + lane];

  float v[32], m15, m16;
  #pragma unroll
  for (int k = 0; k < 32; ++k) v[k] = bf_lo(pr[k]);
  medsel32(v, m15, m16);
  const float oA = fminf(fmaxf(bf_lo(ps), m15), m16) + b2[lane * 2 + 0];

  #pragma unroll
  for (int k = 0; k < 32; ++k) v[k] = bf_hi(pr[k]);
  medsel32(v, m15, m16);
  const float oB = fminf(fmaxf(bf_hi(ps), m15), m16) + b2[lane * 2 + 1];

  float m = fmaxf(oA, oB);
  #pragma unroll
  for (int d = 1; d < 32; d <<= 1) m = fmaxf(m, __shfl_xor(m, d, 32));
  float s = __expf(oA - m) + __expf(oB - m);
  #pragma unroll
  for (int d = 1; d < 32; d <<= 1) s += __shfl_xor(s, d, 32);
  const float ls = __logf(s);

  *reinterpret_cast<float2*>(&out[i * NC + lane * 2]) =
      make_float2(oA - m - ls, oB - m - ls);
}

// ---------------- launch ----------------
extern "C" void kernel_launch(void* const* d_in, const int* in_sizes, int n_in,
                              void* d_out, int out_size, void* d_ws, size_t ws_size,
                              hipStream_t stream) {
  const float* x   = (const float*)d_in[0];
  const int*   nbr = (const int*)d_in[1];
  const float* W1  = (const float*)d_in[2];
  const float* b1  = (const float*)d_in[3];
  const float* W2  = (const float*)d_in[4];
  const float* b2  = (const float*)d_in[5];
  float* outp = (float*)d_out;

  __hip_bfloat16* h0b = (__hip_bfloat16*)d_ws;                                  // 7.68 MB
  __hip_bfloat16* zb  = (__hip_bfloat16*)((char*)d_ws + (size_t)NN * NH * 2);   // 3.84 MB
  unsigned short* Bp  = (unsigned short*)((char*)d_ws + (size_t)NN * (NH + NC) * 2); // 128 KB

  k0_prepW1<<<32, 256, 0, stream>>>(W1, Bp);
  k1_gemm1<<<(NN + 63) / 64, 256, 0, stream>>>(x, Bp, h0b);
  k2_median1_gemm2<<<NN / 4, 256, 0, stream>>>(h0b, nbr, b1, W2, zb);
  k3_median2_lsm<<<NN / 8, 256, 0, stream>>>(zb, nbr, b2, outp);
}